// Round 8
// baseline (465.772 us; speedup 1.0000x reference)
//
#include <hip/hip_runtime.h>
#include <math.h>

// ---------- types ----------
typedef __bf16 bf16x8 __attribute__((ext_vector_type(8)));
typedef float  f32x4  __attribute__((ext_vector_type(4)));

#define QCHUNK 128
#define NCHUNK 16
#define SLD 136              // LDS row stride (bf16 elems) for 128-wide arrays

__device__ __forceinline__ float bf2f(unsigned short u) {
    union { unsigned int i; float f; } v; v.i = ((unsigned int)u) << 16; return v.f;
}
__device__ __forceinline__ unsigned short f2bf(float f) {
    union { float f; unsigned int i; } v; v.f = f;
    unsigned int x = v.i;
    unsigned int r = (x + 0x7FFFu + ((x >> 16) & 1u)) >> 16;
    return (unsigned short)r;
}
__device__ __forceinline__ uint4 pack8(float4 a, float4 b) {
    uint4 r;
    r.x = (unsigned)f2bf(a.x) | ((unsigned)f2bf(a.y) << 16);
    r.y = (unsigned)f2bf(a.z) | ((unsigned)f2bf(a.w) << 16);
    r.z = (unsigned)f2bf(b.x) | ((unsigned)f2bf(b.y) << 16);
    r.w = (unsigned)f2bf(b.z) | ((unsigned)f2bf(b.w) << 16);
    return r;
}
__device__ __forceinline__ void load_lds16(const void* g, void* l) {
    __builtin_amdgcn_global_load_lds((const __attribute__((address_space(1))) void*)g,
                                     (__attribute__((address_space(3))) void*)l,
                                     16, 0, 0);
}
union bfcvt { uint4 u; bf16x8 h; };

// ---------- convert: x -> x_bf, w_in -> w_in_bf (padded 3456 rows, zero-filled) ----------
__global__ __launch_bounds__(256)
void convert_kernel(const float* __restrict__ x, const float* __restrict__ w_in,
                    unsigned short* __restrict__ x_bf, unsigned short* __restrict__ w_in_bf) {
    int idx = blockIdx.x * 256 + threadIdx.x;      // 8 elems each
    const int NX  = 8192 * 768 / 8;                // 786432
    const int NW1 = 3456 * 768 / 8;                // 331776 (padded)
    const int NW1r = 3352 * 768 / 8;               // 321792 (real)
    if (idx < NX) {
        const float* s = x + (size_t)idx * 8;
        *(uint4*)(x_bf + (size_t)idx * 8) = pack8(*(const float4*)s, *(const float4*)(s + 4));
    } else if (idx < NX + NW1) {
        int j = idx - NX;
        uint4 v = make_uint4(0u, 0u, 0u, 0u);
        if (j < NW1r) {
            const float* s = w_in + (size_t)j * 8;
            v = pack8(*(const float4*)s, *(const float4*)(s + 4));
        }
        *(uint4*)(w_in_bf + (size_t)j * 8) = v;
    }
}

// ---------- convert w_out -> bf16 ----------
__global__ __launch_bounds__(256)
void convert_wout_kernel(const float* __restrict__ w_out, unsigned short* __restrict__ w_out_bf) {
    int idx = blockIdx.x * 256 + threadIdx.x;      // 147456 total
    const float* s = w_out + (size_t)idx * 8;
    *(uint4*)(w_out_bf + (size_t)idx * 8) = pack8(*(const float4*)s, *(const float4*)(s + 4));
}

// ---------- GEMM 128x128 (m97-style), bf16 in, global_load_lds staging ----------
template <bool OUT_F32, bool RESID>
__global__ __launch_bounds__(256)
void gemm_lds(const unsigned short* __restrict__ A, const unsigned short* __restrict__ Bw,
              void* __restrict__ Outp, const float* __restrict__ Resid,
              int NT, int N_real, int K, int lda) {
    __shared__ __align__(16) __bf16 As[128 * 32];
    __shared__ __align__(16) __bf16 Bs[128 * 32];

    const int tid = threadIdx.x;
    const int blk = blockIdx.x;
    const int xcd = blk & 7, j = blk >> 3;
    const int m0 = (xcd * 8 + (j & 7)) * 128;
    const int n0 = (j >> 3) * 128;

    const int wave = tid >> 6, lane = tid & 63;
    const int wm = (wave & 1) * 64, wn = (wave >> 1) * 64;
    const int lr = lane & 15, q = lane >> 4;

    const int srow = tid >> 2;
    const int scol = (tid & 3) << 3;
    const unsigned short* ag  = A + (size_t)(m0 + srow) * lda + scol;
    const unsigned short* ag2 = A + (size_t)(m0 + 64 + srow) * lda + scol;
    const unsigned short* bg  = Bw + (size_t)(n0 + srow) * K + scol;
    const unsigned short* bg2 = Bw + (size_t)(n0 + 64 + srow) * K + scol;
    __bf16* asd  = As + tid * 8;
    __bf16* asd2 = As + 2048 + tid * 8;
    __bf16* bsd  = Bs + tid * 8;
    __bf16* bsd2 = Bs + 2048 + tid * 8;

    f32x4 acc[4][4] = {};

    for (int k0 = 0; k0 < K; k0 += 32) {
        load_lds16(ag + k0, asd);
        load_lds16(ag2 + k0, asd2);
        load_lds16(bg + k0, bsd);
        load_lds16(bg2 + k0, bsd2);
        __syncthreads();

        bf16x8 af[4], bfr[4];
        #pragma unroll
        for (int t = 0; t < 4; ++t) {
            af[t]  = *(const bf16x8*)(As + (wm + t * 16 + lr) * 32 + q * 8);
            bfr[t] = *(const bf16x8*)(Bs + (wn + t * 16 + lr) * 32 + q * 8);
        }
        #pragma unroll
        for (int ti = 0; ti < 4; ++ti)
            #pragma unroll
            for (int tj = 0; tj < 4; ++tj)
                acc[ti][tj] = __builtin_amdgcn_mfma_f32_16x16x32_bf16(af[ti], bfr[tj], acc[ti][tj], 0, 0, 0);
        __syncthreads();
    }

    #pragma unroll
    for (int ti = 0; ti < 4; ++ti) {
        #pragma unroll
        for (int r = 0; r < 4; ++r) {
            int m = m0 + wm + ti * 16 + q * 4 + r;
            #pragma unroll
            for (int tj = 0; tj < 4; ++tj) {
                int n = n0 + wn + tj * 16 + lr;
                if (n < N_real) {
                    float v = acc[ti][tj][r];
                    if (RESID) v += Resid[(size_t)m * N_real + n];
                    if (OUT_F32) ((float*)Outp)[(size_t)m * N_real + n] = v;
                    else ((unsigned short*)Outp)[(size_t)m * N_real + n] = f2bf(v);
                }
            }
        }
    }
}

// ---------- GEMM 128x64 tile (for N=768: 12 n-tiles -> 768 blocks) ----------
template <bool OUT_F32, bool RESID>
__global__ __launch_bounds__(256)
void gemm_lds64(const unsigned short* __restrict__ A, const unsigned short* __restrict__ Bw,
                void* __restrict__ Outp, const float* __restrict__ Resid,
                int N_real, int K, int lda) {
    __shared__ __align__(16) __bf16 As[128 * 32];
    __shared__ __align__(16) __bf16 Bs[64 * 32];

    const int tid = threadIdx.x;
    const int blk = blockIdx.x;
    const int xcd = blk & 7, j = blk >> 3;
    const int m0 = (xcd * 8 + (j & 7)) * 128;
    const int n0 = (j >> 3) * 64;

    const int wave = tid >> 6, lane = tid & 63;
    const int wm = (wave & 1) * 64, wn = (wave >> 1) * 32;
    const int lr = lane & 15, q = lane >> 4;

    const int srow = tid >> 2;
    const int scol = (tid & 3) << 3;
    const unsigned short* ag  = A + (size_t)(m0 + srow) * lda + scol;
    const unsigned short* ag2 = A + (size_t)(m0 + 64 + srow) * lda + scol;
    const unsigned short* bg  = Bw + (size_t)(n0 + srow) * K + scol;
    __bf16* asd  = As + tid * 8;
    __bf16* asd2 = As + 2048 + tid * 8;
    __bf16* bsd  = Bs + tid * 8;

    f32x4 acc[4][2] = {};

    for (int k0 = 0; k0 < K; k0 += 32) {
        load_lds16(ag + k0, asd);
        load_lds16(ag2 + k0, asd2);
        load_lds16(bg + k0, bsd);
        __syncthreads();

        bf16x8 af[4], bfr[2];
        #pragma unroll
        for (int t = 0; t < 4; ++t)
            af[t] = *(const bf16x8*)(As + (wm + t * 16 + lr) * 32 + q * 8);
        #pragma unroll
        for (int t = 0; t < 2; ++t)
            bfr[t] = *(const bf16x8*)(Bs + (wn + t * 16 + lr) * 32 + q * 8);
        #pragma unroll
        for (int ti = 0; ti < 4; ++ti)
            #pragma unroll
            for (int tj = 0; tj < 2; ++tj)
                acc[ti][tj] = __builtin_amdgcn_mfma_f32_16x16x32_bf16(af[ti], bfr[tj], acc[ti][tj], 0, 0, 0);
        __syncthreads();
    }

    #pragma unroll
    for (int ti = 0; ti < 4; ++ti) {
        #pragma unroll
        for (int r = 0; r < 4; ++r) {
            int m = m0 + wm + ti * 16 + q * 4 + r;
            #pragma unroll
            for (int tj = 0; tj < 2; ++tj) {
                int n = n0 + wn + tj * 16 + lr;
                float v = acc[ti][tj][r];
                if (RESID) v += Resid[(size_t)m * N_real + n];
                if (OUT_F32) ((float*)Outp)[(size_t)m * N_real + n] = v;
                else ((unsigned short*)Outp)[(size_t)m * N_real + n] = f2bf(v);
            }
        }
    }
}

// ---------- fused conv(4)+silu+layout ----------
__global__ __launch_bounds__(256)
void conv_fused_kernel(const unsigned short* __restrict__ zx,
                       const float* __restrict__ cw, const float* __restrict__ cb,
                       unsigned short* __restrict__ xT, unsigned short* __restrict__ bT,
                       unsigned short* __restrict__ Brow, unsigned short* __restrict__ Crow) {
    __shared__ unsigned short outt[64][66];
    __shared__ float cwl[64][4];
    __shared__ float cbl[64];

    int blk = blockIdx.x;
    int cht = blk % 28;
    int tt  = (blk / 28) % 32;
    int b   = blk / (28 * 32);
    int ch0 = cht * 64, t0 = tt * 64;
    int tid = threadIdx.x;
    int tx = tid & 63, ty = tid >> 6;

    if (tid < 64) cbl[tid] = cb[ch0 + tid];
    cwl[tid >> 2][tid & 3] = cw[(ch0 + (tid >> 2)) * 4 + (tid & 3)];
    __syncthreads();

    const unsigned short* zp = zx + (size_t)(b * 2048) * 3352 + 1536 + ch0 + tx;
    float w0 = cwl[tx][0], w1 = cwl[tx][1], w2 = cwl[tx][2], w3 = cwl[tx][3];
    float bias = cbl[tx];
    int tg = t0 + ty * 16;
    float r0 = (tg >= 3) ? bf2f(zp[(size_t)(tg - 3) * 3352]) : 0.f;
    float r1 = (tg >= 2) ? bf2f(zp[(size_t)(tg - 2) * 3352]) : 0.f;
    float r2 = (tg >= 1) ? bf2f(zp[(size_t)(tg - 1) * 3352]) : 0.f;
    #pragma unroll
    for (int k = 0; k < 16; ++k) {
        float cur = bf2f(zp[(size_t)(tg + k) * 3352]);
        float a = bias + r0 * w0 + r1 * w1 + r2 * w2 + cur * w3;
        a = a / (1.f + expf(-a));
        outt[ty * 16 + k][tx] = f2bf(a);
        r0 = r1; r1 = r2; r2 = cur;
    }
    __syncthreads();

    if (ch0 < 1536) {
        unsigned short* dst = xT + ((size_t)(b * 1536 + ch0)) * 2048 + t0;
        #pragma unroll
        for (int k = 0; k < 16; ++k) {
            int chl = ty * 16 + k;
            dst[(size_t)chl * 2048 + tx] = outt[tx][chl];
        }
    } else if (ch0 < 1664) {
        int n0 = ch0 - 1536;
        unsigned short* dstT = bT + ((size_t)(b * 128 + n0)) * 2048 + t0;
        #pragma unroll
        for (int k = 0; k < 16; ++k) {
            int chl = ty * 16 + k;
            dstT[(size_t)chl * 2048 + tx] = outt[tx][chl];
        }
        unsigned short* dstR = Brow + ((size_t)(b * 2048 + t0)) * 128 + n0;
        int tl = tid >> 3, c8 = (tid & 7) << 3;
        #pragma unroll
        for (int it = 0; it < 2; ++it) {
            int t = tl + it * 32;
            unsigned short tmp[8];
            #pragma unroll
            for (int jj = 0; jj < 8; ++jj) tmp[jj] = outt[t][c8 + jj];
            *(uint4*)(dstR + (size_t)t * 128 + c8) = *(uint4*)tmp;
        }
    } else {
        int n0 = ch0 - 1664;
        unsigned short* dstR = Crow + ((size_t)(b * 2048 + t0)) * 128 + n0;
        int tl = tid >> 3, c8 = (tid & 7) << 3;
        #pragma unroll
        for (int it = 0; it < 2; ++it) {
            int t = tl + it * 32;
            unsigned short tmp[8];
            #pragma unroll
            for (int jj = 0; jj < 8; ++jj) tmp[jj] = outt[t][c8 + jj];
            *(uint4*)(dstR + (size_t)t * 128 + c8) = *(uint4*)tmp;
        }
    }
}

// ---------- dt in full f32 -> interleaved (dt, dt*A) float2 ----------
__global__ __launch_bounds__(64)
void dt_kernel(const float* __restrict__ x, const float* __restrict__ w_in,
               const float* __restrict__ dt_bias, const float* __restrict__ A_log,
               float2* __restrict__ dtdA) {
    int row = blockIdx.x;
    int lane = threadIdx.x;
    float xv[12];
    #pragma unroll
    for (int i = 0; i < 12; ++i) xv[i] = x[(size_t)row * 768 + i * 64 + lane];
    for (int h = 0; h < 24; ++h) {
        const float* w = w_in + (size_t)(3328 + h) * 768;
        float acc = 0.f;
        #pragma unroll
        for (int i = 0; i < 12; ++i) acc += xv[i] * w[i * 64 + lane];
        #pragma unroll
        for (int m = 1; m < 64; m <<= 1) acc += __shfl_xor(acc, m);
        if (lane == 0) {
            float v = acc + dt_bias[h];
            float dt = (v > 20.f) ? v : log1pf(expf(v));
            float A = -expf(A_log[h]);
            dtdA[(size_t)row * 24 + h] = make_float2(dt, dt * A);   // (dt, log dA)
        }
    }
}

// ---------- SSD local v2: Ms-only LDS, global MFMA operands, D folded into diagonal ----------
// grid 1536 (bh*16 + c), 256 threads. static LDS ~35 KB -> 4 blocks/CU.
__global__ __launch_bounds__(256)
void ssd_local_kernel(const unsigned short* __restrict__ Brow,
                      const unsigned short* __restrict__ Crow,
                      const float2* __restrict__ dtdA,
                      const unsigned short* __restrict__ xT,
                      const unsigned short* __restrict__ bT,
                      const float* __restrict__ Dh,
                      unsigned short* __restrict__ yb,
                      unsigned short* __restrict__ sst,
                      float* __restrict__ Pbuf) {
    __shared__ __align__(16) __bf16 Ms[128 * SLD];   // 34816 B
    __shared__ float Lc[128];
    __shared__ float dtl[128];

    const int tid = threadIdx.x;
    const int c   = blockIdx.x & 15;
    const int bh  = blockIdx.x >> 4;
    const int b   = bh / 24, h = bh % 24;
    const int t0g = b * 2048 + c * QCHUNK;
    const int wave = tid >> 6, lane = tid & 63;
    const int lr = lane & 15, q = lane >> 4;

    // log-decay prefix scan, single wave
    if (wave == 0) {
        float2 d0 = dtdA[((size_t)(t0g + lane)) * 24 + h];
        float2 d1 = dtdA[((size_t)(t0g + 64 + lane)) * 24 + h];
        float a = d0.y, bs = d1.y;
        #pragma unroll
        for (int off = 1; off < 64; off <<= 1) { float v = __shfl_up(a, off);  if (lane >= off) a += v; }
        #pragma unroll
        for (int off = 1; off < 64; off <<= 1) { float v = __shfl_up(bs, off); if (lane >= off) bs += v; }
        bs += __shfl(a, 63);
        Lc[lane] = a; Lc[lane + 64] = bs;
        dtl[lane] = d0.x; dtl[lane + 64] = d1.x;
    }
    __syncthreads();

    const unsigned short* Crb = Crow + (size_t)t0g * 128;
    const unsigned short* Brb = Brow + (size_t)t0g * 128;

    // P1: G[t][tau] = sum_n C[t][n] * B[tau][n]  (operands straight from global)
    const int wm = (wave & 1) * 64, wn = (wave >> 1) * 64;
    f32x4 g[4][4] = {};
    #pragma unroll
    for (int k0 = 0; k0 < 128; k0 += 32) {
        bf16x8 af[4], bfr[4];
        #pragma unroll
        for (int t = 0; t < 4; ++t) {
            af[t]  = *(const bf16x8*)(Crb + (size_t)(wm + t * 16 + lr) * 128 + k0 + q * 8);
            bfr[t] = *(const bf16x8*)(Brb + (size_t)(wn + t * 16 + lr) * 128 + k0 + q * 8);
        }
        #pragma unroll
        for (int ti = 0; ti < 4; ++ti)
            #pragma unroll
            for (int tj = 0; tj < 4; ++tj)
                g[ti][tj] = __builtin_amdgcn_mfma_f32_16x16x32_bf16(af[ti], bfr[tj], g[ti][tj], 0, 0, 0);
    }

    // P5: masked scale -> Ms[t][tau]; D folded into diagonal
    {
        float Dv = Dh[h];
        float lt_[4], dt_[4];
        #pragma unroll
        for (int tj = 0; tj < 4; ++tj) {
            int tau = wn + tj * 16 + lr;
            lt_[tj] = Lc[tau];
            dt_[tj] = dtl[tau];
        }
        #pragma unroll
        for (int ti = 0; ti < 4; ++ti) {
            #pragma unroll
            for (int r = 0; r < 4; ++r) {
                int t = wm + ti * 16 + q * 4 + r;
                float Lt = Lc[t];
                #pragma unroll
                for (int tj = 0; tj < 4; ++tj) {
                    int tau = wn + tj * 16 + lr;
                    float mv = (tau <= t) ? g[ti][tj][r] * expf(Lt - lt_[tj]) * dt_[tj] : 0.f;
                    if (tau == t) mv += Dv;
                    unsigned short u = f2bf(mv);
                    Ms[t * SLD + tau] = *(__bf16*)&u;
                }
            }
        }
    }

    // P4: s_out[n][p] = sum_tau bT[n][tau] * (xT[p][tau] * wv[tau])   (no barrier needed yet)
    const unsigned short* xTb = xT + ((size_t)(b * 1536 + h * 64)) * 2048 + c * QCHUNK;
    {
        float LQ = Lc[127];
        f32x4 so[2][4] = {};
        const unsigned short* bTb = bT + ((size_t)(b * 128)) * 2048 + c * QCHUNK;
        #pragma unroll
        for (int k0 = 0; k0 < 128; k0 += 32) {
            float wv[8];
            int tb0 = k0 + q * 8;
            #pragma unroll
            for (int jj = 0; jj < 8; ++jj) wv[jj] = expf(LQ - Lc[tb0 + jj]) * dtl[tb0 + jj];
            bf16x8 af[2], bfr[4];
            #pragma unroll
            for (int ti = 0; ti < 2; ++ti) {
                int n = wave * 32 + ti * 16 + lr;
                af[ti] = *(const bf16x8*)(bTb + (size_t)n * 2048 + k0 + q * 8);
            }
            #pragma unroll
            for (int tj = 0; tj < 4; ++tj) {
                uint4 v = *(const uint4*)(xTb + (size_t)(tj * 16 + lr) * 2048 + k0 + q * 8);
                float f0 = bf2f((unsigned short)(v.x & 0xFFFF)) * wv[0];
                float f1 = bf2f((unsigned short)(v.x >> 16))    * wv[1];
                float f2 = bf2f((unsigned short)(v.y & 0xFFFF)) * wv[2];
                float f3 = bf2f((unsigned short)(v.y >> 16))    * wv[3];
                float f4 = bf2f((unsigned short)(v.z & 0xFFFF)) * wv[4];
                float f5 = bf2f((unsigned short)(v.z >> 16))    * wv[5];
                float f6 = bf2f((unsigned short)(v.w & 0xFFFF)) * wv[6];
                float f7 = bf2f((unsigned short)(v.w >> 16))    * wv[7];
                bfcvt cvt;
                cvt.u = pack8(make_float4(f0, f1, f2, f3), make_float4(f4, f5, f6, f7));
                bfr[tj] = cvt.h;
            }
            #pragma unroll
            for (int ti = 0; ti < 2; ++ti)
                #pragma unroll
                for (int tj = 0; tj < 4; ++tj)
                    so[ti][tj] = __builtin_amdgcn_mfma_f32_16x16x32_bf16(af[ti], bfr[tj], so[ti][tj], 0, 0, 0);
        }
        unsigned short* sb = sst + ((size_t)(bh * NCHUNK + c)) * 8192;
        #pragma unroll
        for (int ti = 0; ti < 2; ++ti) {
            #pragma unroll
            for (int r = 0; r < 4; ++r) {
                int n = wave * 32 + ti * 16 + q * 4 + r;
                #pragma unroll
                for (int tj = 0; tj < 4; ++tj) {
                    int p = tj * 16 + lr;
                    sb[n * 64 + p] = f2bf(so[ti][tj][r]);
                }
            }
        }
        if (tid == 0) Pbuf[bh * NCHUNK + c] = expf(Lc[127]);
    }
    __syncthreads();   // Ms writes visible to all waves

    // P6: Y[t][p] = sum_tau Ms[t][tau] * xT[p][tau]  (D already in Ms)
    {
        f32x4 ya[2][4] = {};
        #pragma unroll
        for (int k0 = 0; k0 < 128; k0 += 32) {
            bf16x8 af[2], bfr[4];
            #pragma unroll
            for (int ti = 0; ti < 2; ++ti)
                af[ti] = *(const bf16x8*)(Ms + (wave * 32 + ti * 16 + lr) * SLD + k0 + q * 8);
            #pragma unroll
            for (int tj = 0; tj < 4; ++tj)
                bfr[tj] = *(const bf16x8*)(xTb + (size_t)(tj * 16 + lr) * 2048 + k0 + q * 8);
            #pragma unroll
            for (int ti = 0; ti < 2; ++ti)
                #pragma unroll
                for (int tj = 0; tj < 4; ++tj)
                    ya[ti][tj] = __builtin_amdgcn_mfma_f32_16x16x32_bf16(af[ti], bfr[tj], ya[ti][tj], 0, 0, 0);
        }
        unsigned short* ybb = yb + (size_t)t0g * 1536 + h * 64;
        #pragma unroll
        for (int ti = 0; ti < 2; ++ti) {
            #pragma unroll
            for (int r = 0; r < 4; ++r) {
                int t = wave * 32 + ti * 16 + q * 4 + r;
                #pragma unroll
                for (int tj = 0; tj < 4; ++tj) {
                    int p = tj * 16 + lr;
                    ybb[(size_t)t * 1536 + p] = f2bf(ya[ti][tj][r]);
                }
            }
        }
    }
}

// ---------- combine ----------
__global__ __launch_bounds__(256)
void combine_kernel(const unsigned short* __restrict__ sst,
                    unsigned short* __restrict__ sstT,
                    const float* __restrict__ Pbuf) {
    int flat = blockIdx.x * 256 + threadIdx.x;
    int bh = flat >> 13;
    int pn = flat & 8191;
    int n = pn >> 6, p = pn & 63;
    const unsigned short* sb = sst + (size_t)bh * NCHUNK * 8192;
    unsigned short* tb = sstT + (size_t)bh * NCHUNK * 8192 + p * 128 + n;
    const float* Pb = Pbuf + bh * NCHUNK;
    float s = 0.f;
    #pragma unroll
    for (int c = 0; c < NCHUNK; ++c) {
        float tmp = bf2f(sb[(size_t)c * 8192 + pn]);
        tb[(size_t)c * 8192] = f2bf(s);
        s = Pb[c] * s + tmp;
    }
}

// ---------- SSD inter v2: zero staging; y RMW in bf16 ----------
__global__ __launch_bounds__(256)
void ssd_inter_kernel(const unsigned short* __restrict__ Crow,
                      const float2* __restrict__ dtdA,
                      const unsigned short* __restrict__ sstT,
                      unsigned short* __restrict__ yb) {
    __shared__ float Lc[128];

    const int tid = threadIdx.x;
    const int blk = blockIdx.x;
    const int bh = blk / 15;
    const int c  = blk % 15 + 1;
    const int b = bh / 24, h = bh % 24;
    const int t0g = b * 2048 + c * QCHUNK;
    const int wave = tid >> 6, lane = tid & 63;
    const int lr = lane & 15, q = lane >> 4;

    if (wave == 0) {
        float a = dtdA[((size_t)(t0g + lane)) * 24 + h].y;
        float bs = dtdA[((size_t)(t0g + 64 + lane)) * 24 + h].y;
        #pragma unroll
        for (int off = 1; off < 64; off <<= 1) { float v = __shfl_up(a, off);  if (lane >= off) a += v; }
        #pragma unroll
        for (int off = 1; off < 64; off <<= 1) { float v = __shfl_up(bs, off); if (lane >= off) bs += v; }
        bs += __shfl(a, 63);
        Lc[lane] = a; Lc[lane + 64] = bs;
    }
    __syncthreads();

    const unsigned short* Crb = Crow + (size_t)t0g * 128;
    const unsigned short* stb = sstT + ((size_t)(bh * NCHUNK + c)) * 8192;

    f32x4 ya[2][4] = {};
    #pragma unroll
    for (int k0 = 0; k0 < 128; k0 += 32) {
        bf16x8 af[2], bfr[4];
        #pragma unroll
        for (int ti = 0; ti < 2; ++ti)
            af[ti] = *(const bf16x8*)(Crb + (size_t)(wave * 32 + ti * 16 + lr) * 128 + k0 + q * 8);
        #pragma unroll
        for (int tj = 0; tj < 4; ++tj)
            bfr[tj] = *(const bf16x8*)(stb + (size_t)(tj * 16 + lr) * 128 + k0 + q * 8);
        #pragma unroll
        for (int ti = 0; ti < 2; ++ti)
            #pragma unroll
            for (int tj = 0; tj < 4; ++tj)
                ya[ti][tj] = __builtin_amdgcn_mfma_f32_16x16x32_bf16(af[ti], bfr[tj], ya[ti][tj], 0, 0, 0);
    }
    unsigned short* ybb = yb + (size_t)t0g * 1536 + h * 64;
    #pragma unroll
    for (int ti = 0; ti < 2; ++ti) {
        #pragma unroll
        for (int r = 0; r < 4; ++r) {
            int t = wave * 32 + ti * 16 + q * 4 + r;
            float sc = expf(Lc[t]);
            #pragma unroll
            for (int tj = 0; tj < 4; ++tj) {
                int p = tj * 16 + lr;
                unsigned short* yp = ybb + (size_t)t * 1536 + p;
                *yp = f2bf(bf2f(*yp) + sc * ya[ti][tj][r]);
            }
        }
    }
}

// ---------- gated RMSNorm (vectorized): y bf16, writes bf16 into zx cols [1536,3072) ----------
__global__ __launch_bounds__(256)
void norm_kernel(const unsigned short* __restrict__ yb,
                 unsigned short* __restrict__ zx,
                 const float* __restrict__ nw) {
    int row = blockIdx.x;
    const unsigned short* yr = yb + (size_t)row * 1536;
    unsigned short* zr = zx + (size_t)row * 3352;
    int tid = threadIdx.x;
    float u[8];
    float ss = 0.f;
    int c0 = tid * 8;
    if (tid < 192) {
        uint4 yv = *(const uint4*)(yr + c0);
        uint4 zv = *(const uint4*)(zr + c0);
        unsigned short yu[8] = {(unsigned short)(yv.x & 0xFFFF), (unsigned short)(yv.x >> 16),
                                (unsigned short)(yv.y & 0xFFFF), (unsigned short)(yv.y >> 16),
                                (unsigned short)(yv.z & 0xFFFF), (unsigned short)(yv.z >> 16),
                                (unsigned short)(yv.w & 0xFFFF), (unsigned short)(yv.w >> 16)};
        unsigned short zu[8] = {(unsigned short)(zv.x & 0xFFFF), (unsigned short)(zv.x >> 16),
                                (unsigned short)(zv.y & 0xFFFF), (unsigned short)(zv.y >> 16),
                                (unsigned short)(zv.z & 0xFFFF), (unsigned short)(zv.z >> 16),
                                (unsigned short)(zv.w & 0xFFFF), (unsigned short)(zv.w >> 16)};
        #pragma unroll
        for (int i = 0; i < 8; ++i) {
            float z = bf2f(zu[i]);
            float uu = bf2f(yu[i]) * (z / (1.f + expf(-z)));
            u[i] = uu;
            ss += uu * uu;
        }
    } else {
        #pragma unroll
        for (int i = 0; i < 8; ++i) u[i] = 0.f;
    }
    #pragma unroll
    for (int m = 1; m < 64; m <<= 1) ss += __shfl_xor(ss, m);
    __shared__ float red[4];
    if ((tid & 63) == 0) red[tid >> 6] = ss;
    __syncthreads();
    float tot = red[0] + red[1] + red[2] + red[3];
    float inv = rsqrtf(tot * (1.f / 1536.f) + 1e-5f);
    if (tid < 192) {
        const float* nwp = nw + c0;
        float4 o0 = make_float4(u[0] * inv * nwp[0], u[1] * inv * nwp[1],
                                u[2] * inv * nwp[2], u[3] * inv * nwp[3]);
        float4 o1 = make_float4(u[4] * inv * nwp[4], u[5] * inv * nwp[5],
                                u[6] * inv * nwp[6], u[7] * inv * nwp[7]);
        *(uint4*)(zr + 1536 + c0) = pack8(o0, o1);
    }
}

// ---------- launch ----------
extern "C" void kernel_launch(void* const* d_in, const int* in_sizes, int n_in,
                              void* d_out, int out_size, void* d_ws, size_t ws_size,
                              hipStream_t stream) {
    const float* x       = (const float*)d_in[0];
    const float* w_in    = (const float*)d_in[1];
    const float* conv_w  = (const float*)d_in[2];
    const float* conv_b  = (const float*)d_in[3];
    const float* dt_bias = (const float*)d_in[4];
    const float* A_log   = (const float*)d_in[5];
    const float* Dp      = (const float*)d_in[6];
    const float* nw      = (const float*)d_in[7];
    const float* w_out   = (const float*)d_in[8];
    float* out = (float*)d_out;

    char* ws = (char*)d_ws;
    const size_t off_zx   = 0;                        // 8192*3352 bf16 = 54,919,168
    const size_t off_A    = off_zx + 54919168;        // region A (58,720,256 reserved)
    const size_t off_xT   = off_A;                    // 25,165,824 (sstT + w_out_bf alias later)
    const size_t off_bT   = off_A + 25165824;         // 2,097,152
    const size_t off_Brow = off_A + 27262976;         // 2,097,152
    const size_t off_Crow = off_A + 29360128;         // 2,097,152
    const size_t off_dtdA = off_A + 58720256;         // 1,572,864
    const size_t off_y    = off_dtdA + 1572864;       // yb bf16: 25,165,824 (x_bf aliases head)
    const size_t off_sst  = off_y + 25165824;         // 25,165,824 (w_in_bf aliases head)
    const size_t off_P    = off_sst + 25165824;       // 6,144

    unsigned short* zx   = (unsigned short*)(ws + off_zx);
    unsigned short* xT   = (unsigned short*)(ws + off_xT);
    unsigned short* bT   = (unsigned short*)(ws + off_bT);
    unsigned short* Brow = (unsigned short*)(ws + off_Brow);
    unsigned short* Crow = (unsigned short*)(ws + off_Crow);
    float2* dtdA = (float2*)(ws + off_dtdA);
    unsigned short* yb   = (unsigned short*)(ws + off_y);
    unsigned short* sst  = (unsigned short*)(ws + off_sst);
    unsigned short* sstT = xT;                        // xT dead after ssd_local
    float* Pbuf = (float*)(ws + off_P);

    // transient aliases
    unsigned short* x_bf     = (unsigned short*)(ws + off_y);    // gemm1 only (before yb written)
    unsigned short* w_in_bf  = (unsigned short*)(ws + off_sst);  // gemm1 only (before sst written)
    unsigned short* w_out_bf = (unsigned short*)(ws + off_xT);   // written after sstT dead

    // 0. convert x, w_in -> bf16
    convert_kernel<<<4368, 256, 0, stream>>>(x, w_in, x_bf, w_in_bf);
    // 1. in_proj (M=8192, N=3352 padded 3456, K=768)
    gemm_lds<false, false><<<64 * 27, 256, 0, stream>>>(x_bf, w_in_bf, zx, nullptr, 27, 3352, 768, 768);
    // 2. fused conv + silu + layout
    conv_fused_kernel<<<3584, 256, 0, stream>>>(zx, conv_w, conv_b, xT, bT, Brow, Crow);
    // 3. dt / log-dA (full f32)
    dt_kernel<<<8192, 64, 0, stream>>>(x, w_in, dt_bias, A_log, dtdA);
    // 4. SSD local
    ssd_local_kernel<<<1536, 256, 0, stream>>>(Brow, Crow, dtdA, xT, bT, Dp, yb, sst, Pbuf);
    // 5. combine
    combine_kernel<<<3072, 256, 0, stream>>>(sst, sstT, Pbuf);
    // 6. SSD inter
    ssd_inter_kernel<<<1440, 256, 0, stream>>>(Crow, dtdA, sstT, yb);
    // 6.5 convert w_out -> bf16
    convert_wout_kernel<<<576, 256, 0, stream>>>(w_out, w_out_bf);
    // 7. gated RMSNorm
    norm_kernel<<<8192, 256, 0, stream>>>(yb, zx, nw);
    // 8. out_proj + residual (128x64 tiles, 768 blocks)
    gemm_lds64<true, true><<<768, 256, 0, stream>>>(zx + 1536, w_out_bf, out, x, 768, 1536, 3352);
}